// Round 2
// baseline (1016.871 us; speedup 1.0000x reference)
//
#include <hip/hip_runtime.h>

// ---------------------------------------------------------------------------
// SpectrumGenerator: 5-layer MLP (leaky_relu 0.2) + linear interp.
// dims: 128 -> 512 -> 1024 -> 2048 -> 4096 -> 35582 ; batch 64 ; 4096 obs pts
//
// R4 = R3 resubmit (R3 bench was an infra failure, no counters) with tiny
// hardening: plain double ops for the interp candidate index (fixups make it
// exact anyway); __dadd_rn/__dmul_rn kept only where bit-exactness vs the
// host-built f32 grid matters.
//
// R3 changes vs R2:
//  - epilogues of L0..L2 fused into next gemm's A-staging (sum S partials +
//    bias + leaky while filling LDS; ping-pong partial buffers). 11 -> 7
//    dispatches.
//  - interp: analytic searchsorted over the 7 uniform grid segments; no gs
//    buffer, no build_sorted kernel, no 16-deep dependent-load chain.
//  - layer4 emits spec in SORTED column order (W4 row = sorted_to_orig(p),
//    still two contiguous streaming runs); interp reads adjacent cols.
// ---------------------------------------------------------------------------

#define NOUT   35582
#define BATCH  64
#define NOBS   4096
#define ROT    25604   // count of low-wavelength block (sorted first)
#define HIOFF  9978    // orig offset of low-wavelength block

typedef __bf16 bf16_t;
typedef __attribute__((ext_vector_type(8))) __bf16 bf16x8;
typedef __attribute__((ext_vector_type(4))) __bf16 bf16x4;
typedef __attribute__((ext_vector_type(4))) float f32x4;

__device__ __forceinline__ int sorted_to_orig(int p) {
    return (p < ROT) ? (p + HIOFF) : (p - ROT);
}

// ---------------- fp32 FC partial GEMM: part[s] = A @ W^T (K-chunk) --------
// A-source: S_in==0 -> Araw (row stride K).  S_in>0 -> A(m,c) =
//   leaky(sum_{s<S_in} partIn[s*64*K + m*K + c] + biasIn[c])   (fused epi).
// Block: 256 thr, 64x64 tile, BK = 32. gridDim.y = K/KC chunks; partial tile
// stored to partOut + by*64*N.
__global__ __launch_bounds__(256) void fc_gemm(
    const float* __restrict__ Araw, const float* __restrict__ partIn,
    const float* __restrict__ biasIn, const float* __restrict__ W,
    float* __restrict__ partOut, int K, int N, int KC, int S_in)
{
    __shared__ float As[32][68];   // [k][m]
    __shared__ float Bs[32][68];   // [k][n]

    const int t  = threadIdx.x;
    const int n0 = blockIdx.x * 64;
    const int kbase = blockIdx.y * KC;
    const int tx = t & 15;
    const int ty = t >> 4;

    float acc[4][4] = {};

    for (int k0 = kbase; k0 < kbase + KC; k0 += 32) {
        __syncthreads();
#pragma unroll
        for (int f = 0; f < 2; ++f) {
            int e  = (t + 256 * f) * 4;
            int m  = e >> 5;
            int kk = e & 31;
            float4 v;
            if (S_in == 0) {
                v = *(const float4*)(Araw + (size_t)m * K + k0 + kk);
            } else {
                const float* p = partIn + (size_t)m * K + k0 + kk;
                v = *(const float4*)p;
                for (int s = 1; s < S_in; ++s) {
                    float4 q = *(const float4*)(p + (size_t)s * 64 * K);
                    v.x += q.x; v.y += q.y; v.z += q.z; v.w += q.w;
                }
                float4 b = *(const float4*)(biasIn + k0 + kk);
                v.x += b.x; v.y += b.y; v.z += b.z; v.w += b.w;
                v.x = v.x > 0.f ? v.x : 0.2f * v.x;
                v.y = v.y > 0.f ? v.y : 0.2f * v.y;
                v.z = v.z > 0.f ? v.z : 0.2f * v.z;
                v.w = v.w > 0.f ? v.w : 0.2f * v.w;
            }
            As[kk + 0][m] = v.x; As[kk + 1][m] = v.y;
            As[kk + 2][m] = v.z; As[kk + 3][m] = v.w;
        }
#pragma unroll
        for (int f = 0; f < 2; ++f) {
            int e  = (t + 256 * f) * 4;
            int n  = e >> 5;
            int kk = e & 31;
            float4 v = *(const float4*)(W + (size_t)(n0 + n) * K + k0 + kk);
            Bs[kk + 0][n] = v.x; Bs[kk + 1][n] = v.y;
            Bs[kk + 2][n] = v.z; Bs[kk + 3][n] = v.w;
        }
        __syncthreads();
#pragma unroll
        for (int kk = 0; kk < 32; ++kk) {
            float4 av = *(const float4*)&As[kk][ty * 4];
            float4 bv = *(const float4*)&Bs[kk][tx * 4];
            float a[4] = {av.x, av.y, av.z, av.w};
            float b[4] = {bv.x, bv.y, bv.z, bv.w};
#pragma unroll
            for (int i = 0; i < 4; ++i)
#pragma unroll
                for (int j = 0; j < 4; ++j) acc[i][j] += a[i] * b[j];
        }
    }

    float* p = partOut + (size_t)blockIdx.y * 64 * N;
#pragma unroll
    for (int i = 0; i < 4; ++i) {
        int m = ty * 4 + i;
#pragma unroll
        for (int j = 0; j < 4; ++j)
            p[(size_t)m * N + n0 + tx * 4 + j] = acc[i][j];
    }
}

// ---------------- FC epilogue (L3 only): h4b = bf16(leaky(sum part + b)) ---
__global__ __launch_bounds__(256) void fc_epi(
    const float* __restrict__ part, const float* __restrict__ bias,
    float* __restrict__ out, bf16_t* __restrict__ out_bf, int N, int S)
{
    int idx = (blockIdx.x * 256 + threadIdx.x) * 4;   // flat elem index
    int n = idx & (N - 1);                            // N is a power of 2
    float4 v = make_float4(0.f, 0.f, 0.f, 0.f);
    for (int s = 0; s < S; ++s) {
        float4 p = *(const float4*)(part + (size_t)s * 64 * N + idx);
        v.x += p.x; v.y += p.y; v.z += p.z; v.w += p.w;
    }
    float4 b = *(const float4*)(bias + n);
    v.x += b.x; v.y += b.y; v.z += b.z; v.w += b.w;
    v.x = v.x > 0.f ? v.x : 0.2f * v.x;
    v.y = v.y > 0.f ? v.y : 0.2f * v.y;
    v.z = v.z > 0.f ? v.z : 0.2f * v.z;
    v.w = v.w > 0.f ? v.w : 0.2f * v.w;
    if (out) *(float4*)(out + idx) = v;
    if (out_bf) {
        bf16x4 o;
        o[0] = (bf16_t)v.x; o[1] = (bf16_t)v.y;
        o[2] = (bf16_t)v.z; o[3] = (bf16_t)v.w;
        *(bf16x4*)(out_bf + idx) = o;
    }
}

// ---------------- layer 4: spec_sorted = Abf(64x4096) @ W4^T + b4 ----------
// mfma_f32_16x16x32_bf16. Wave handles 16 consecutive SORTED cols p; the W4
// row is sorted_to_orig(p) (two contiguous runs -> streaming stays coalesced).
__global__ __launch_bounds__(256) void layer4_kernel(
    const bf16_t* __restrict__ Abf, const float* __restrict__ W,
    const float* __restrict__ bias, float* __restrict__ spec)
{
    const int lane = threadIdx.x & 63;
    const int wave = threadIdx.x >> 6;
    const int c16  = lane & 15;
    const int quad = lane >> 4;
    const int p    = blockIdx.x * 64 + wave * 16 + c16;   // sorted col
    const int ps   = p < NOUT ? p : NOUT - 1;             // clamp loads
    const int nc   = sorted_to_orig(ps);                  // orig W4/b4 row

    const float*  wp = W   + (size_t)nc * 4096 + quad * 8;
    const bf16_t* ap = Abf + (size_t)c16 * 4096 + quad * 8;

    f32x4 acc[4] = {};

    for (int s = 0; s < 128; ++s) {                // 128 k-steps of 32
        float4 w0 = *(const float4*)(wp);
        float4 w1 = *(const float4*)(wp + 4);
        wp += 32;
        bf16x8 bv;
        bv[0] = (bf16_t)w0.x; bv[1] = (bf16_t)w0.y;
        bv[2] = (bf16_t)w0.z; bv[3] = (bf16_t)w0.w;
        bv[4] = (bf16_t)w1.x; bv[5] = (bf16_t)w1.y;
        bv[6] = (bf16_t)w1.z; bv[7] = (bf16_t)w1.w;
#pragma unroll
        for (int mt = 0; mt < 4; ++mt) {
            bf16x8 av = *(const bf16x8*)(ap + (size_t)mt * 16 * 4096 + s * 32);
            acc[mt] = __builtin_amdgcn_mfma_f32_16x16x32_bf16(av, bv, acc[mt], 0, 0, 0);
        }
    }

    if (p < NOUT) {
        float bq = bias[nc];
#pragma unroll
        for (int mt = 0; mt < 4; ++mt)
#pragma unroll
            for (int r = 0; r < 4; ++r) {
                int m = mt * 16 + quad * 4 + r;
                spec[(size_t)m * NOUT + p] = acc[mt][r] + bq;
            }
    }
}

// ---------------- analytic sorted-grid ------------------------------------
// Sorted segments: (start, step, count, base)
//  (4700,.05,4601,0)(5630,.05,5001,4601)(6420,.05,7601,9602)(7500,.05,8401,17203)
//  (15050,.2,4001,25604)(15870,.2,2851,29605)(16475,.2,3126,32456)
// Grid value must be bit-exact vs host: f64 start + step*k, then f32 cast.
// __dadd_rn/__dmul_rn forbid FMA contraction (would change bits vs host).
__device__ __forceinline__ float grid_val(int p) {
    double s, st; int b;
    if (p < ROT) {
        st = 0.05;
        if      (p < 4601)  { s = 4700.0; b = 0; }
        else if (p < 9602)  { s = 5630.0; b = 4601; }
        else if (p < 17203) { s = 6420.0; b = 9602; }
        else                { s = 7500.0; b = 17203; }
    } else {
        st = 0.2;
        if      (p < 29605) { s = 15050.0; b = 25604; }
        else if (p < 32456) { s = 15870.0; b = 29605; }
        else                { s = 16475.0; b = 32456; }
    }
    return (float)__dadd_rn(s, __dmul_rn(st, (double)(p - b)));
}

// Exact searchsorted-left: first i with gs[i] >= x.
__device__ __forceinline__ int search_idx(float x) {
    if (!(x > 4700.0f)) return 0;
    double s = 4700.0, st = 0.05; int b = 0, n = 4601;
    if (x > 5630.0f)  { s = 5630.0;            b = 4601;  n = 5001; }
    if (x > 6420.0f)  { s = 6420.0;            b = 9602;  n = 7601; }
    if (x > 7500.0f)  { s = 7500.0;            b = 17203; n = 8401; }
    if (x > 15050.0f) { s = 15050.0; st = 0.2; b = 25604; n = 4001; }
    if (x > 15870.0f) { s = 15870.0;           b = 29605; n = 2851; }
    if (x > 16475.0f) { s = 16475.0;           b = 32456; n = 3126; }
    // past the last point of this segment -> first point of next segment
    float gl = (float)__dadd_rn(s, __dmul_rn(st, (double)(n - 1)));
    if (x > gl) return b + n;
    // candidate from continuous math (plain double ops), exact +-1 fixups
    // against the bit-exact f32 grid values
    double tt = ceil(((double)x - s) / st);
    int ti = (int)tt;
    ti = ti < 1 ? 1 : (ti > n - 1 ? n - 1 : ti);
#pragma unroll
    for (int r = 0; r < 2; ++r)
        if (ti >= 2 && (float)__dadd_rn(s, __dmul_rn(st, (double)(ti - 1))) >= x) --ti;
#pragma unroll
    for (int r = 0; r < 2; ++r)
        if (ti < n - 1 && (float)__dadd_rn(s, __dmul_rn(st, (double)ti)) < x) ++ti;
    return b + ti;
}

// ---------------- interpolation (spec in sorted layout) --------------------
__global__ __launch_bounds__(256) void interp_kernel(
    const float* __restrict__ spec, const float* __restrict__ obs,
    float* __restrict__ out)
{
    int idx = blockIdx.x * 256 + threadIdx.x;
    if (idx >= BATCH * NOBS) return;
    int m = idx >> 12;                 // NOBS = 4096
    float x = obs[idx];

    int i = search_idx(x);
    int j = i < 1 ? 1 : (i > NOUT - 1 ? NOUT - 1 : i);

    float x0 = grid_val(j - 1);
    float x1 = grid_val(j);
    const float* sp = spec + (size_t)m * NOUT;
    float y0 = sp[j - 1], y1 = sp[j];
    float t = (x - x0) / (x1 - x0);
    out[idx] = y0 + t * (y1 - y0);
}

// ---------------------------------------------------------------------------
extern "C" void kernel_launch(void* const* d_in, const int* in_sizes, int n_in,
                              void* d_out, int out_size, void* d_ws, size_t ws_size,
                              hipStream_t stream)
{
    const float* W0 = (const float*)d_in[0];
    const float* b0 = (const float*)d_in[1];
    const float* W1 = (const float*)d_in[2];
    const float* b1 = (const float*)d_in[3];
    const float* W2 = (const float*)d_in[4];
    const float* b2 = (const float*)d_in[5];
    const float* W3 = (const float*)d_in[6];
    const float* b3 = (const float*)d_in[7];
    const float* W4 = (const float*)d_in[8];
    const float* b4 = (const float*)d_in[9];
    const float* z  = (const float*)d_in[10];
    const float* obs  = (const float*)d_in[11];
    float* out = (float*)d_out;

    char* ws = (char*)d_ws;
    float*  pA   = (float*)(ws);                 // max 8*64*2048*4 = 4 MB
    float*  pB   = (float*)(ws + 4194304);       // max 8*64*4096*4 = 8 MB
    bf16_t* h4b  = (bf16_t*)(ws + 12582912);     // 64*4096*2 = 512 KB
    float*  spec = (float*)(ws + 13107200);      // 64*35582*4 = 9108992

    // L0: A=z direct, K=128,  N=512,  KC=32  -> grid 8x4,  4 partial chunks
    fc_gemm<<<dim3(8, 4),   256, 0, stream>>>(z, nullptr, nullptr, W0, pA, 128,  512,  32,  0);
    // L1: A=leaky(sum4 pA + b0), K=512,  N=1024, KC=64  -> grid 16x8
    fc_gemm<<<dim3(16, 8),  256, 0, stream>>>(nullptr, pA, b0, W1, pB, 512,  1024, 64,  4);
    // L2: A=leaky(sum8 pB + b1), K=1024, N=2048, KC=128 -> grid 32x8
    fc_gemm<<<dim3(32, 8),  256, 0, stream>>>(nullptr, pB, b1, W2, pA, 1024, 2048, 128, 8);
    // L3: A=leaky(sum8 pA + b2), K=2048, N=4096, KC=256 -> grid 64x8
    fc_gemm<<<dim3(64, 8),  256, 0, stream>>>(nullptr, pA, b2, W3, pB, 2048, 4096, 256, 8);
    // epi3: h4b = bf16(leaky(sum8 pB + b3))
    fc_epi <<<dim3(4096 * 64 / 1024), 256, 0, stream>>>(pB, b3, nullptr, h4b, 4096, 8);

    // layer 4: bf16 MFMA, full K, bias fused, sorted-column stores
    layer4_kernel<<<dim3((NOUT + 63) / 64), 256, 0, stream>>>(h4b, W4, b4, spec);

    // interp: analytic searchsorted, no gs buffer
    interp_kernel<<<dim3((BATCH * NOBS + 255) / 256), 256, 0, stream>>>(spec, obs, out);
}